// Round 1
// baseline (78.712 us; speedup 1.0000x reference)
//
#include <hip/hip_runtime.h>
#include <math.h>

namespace {

constexpr int NU   = 3;    // U
constexpr int DPN  = 128;  // DP
constexpr int TOPK = 32;   // K
constexpr int NB   = 64;   // B
constexpr int NCAND = 119; // sum_{r=0..31} floor(32/(r+1))

// One block per batch row. 128 threads.
__global__ __launch_bounds__(DPN) void kron_topk_kernel(
    const float* __restrict__ z, const float* __restrict__ log_tau,
    float* __restrict__ out) {
  const int row = blockIdx.x;
  const int tid = threadIdx.x;

  __shared__ float p[NU][DPN];      // softmax probabilities
  __shared__ float red[DPN];        // reduction scratch
  __shared__ float sval[NU][TOPK];  // per-factor top-32 values, sorted desc
  __shared__ int   sidx[NU][TOPK];  // per-factor top-32 indices
  __shared__ float cval[DPN];       // stage candidates
  __shared__ int   cidx[DPN];
  __shared__ float aval[TOPK];      // running stage result (sorted)
  __shared__ int   aidx[TOPK];

  const float tau = expf(log_tau[0]);

  // ---- softmax over each of the NU segments (matches jax.nn.softmax rounding)
  for (int u = 0; u < NU; ++u) {
    float x = z[row * (NU * DPN) + u * DPN + tid] / tau;
    red[tid] = x;
    __syncthreads();
    for (int s = DPN / 2; s > 0; s >>= 1) {
      if (tid < s) red[tid] = fmaxf(red[tid], red[tid + s]);
      __syncthreads();
    }
    float m = red[0];
    __syncthreads();
    float e = expf(x - m);
    red[tid] = e;
    __syncthreads();
    for (int s = DPN / 2; s > 0; s >>= 1) {
      if (tid < s) red[tid] += red[tid + s];
      __syncthreads();
    }
    float denom = red[0];
    __syncthreads();
    p[u][tid] = e / denom;
    __syncthreads();
  }

  // ---- per-factor exact top-32 via rank-by-count (desc value, asc index)
  for (int u = 0; u < NU; ++u) {
    float v = p[u][tid];
    int rank = 0;
    for (int j = 0; j < DPN; ++j) {
      float w = p[u][j];
      rank += (w > v) || (w == v && j < tid);
    }
    if (rank < TOPK) { sval[u][rank] = v; sidx[u][rank] = tid; }
  }
  __syncthreads();

  // ---- stage chain: A := top32(p0); A := top32(A x p_u) for u = 1,2
  if (tid < TOPK) { aval[tid] = sval[0][tid]; aidx[tid] = sidx[0][tid]; }
  __syncthreads();

  for (int u = 1; u < NU; ++u) {
    // Enumerate candidate pairs (r,s) with (r+1)(s+1) <= 32: only these can
    // be in the top-32 of the product set (both lists sorted descending).
    float v = -1.0f;             // pad: ranks last (all probs > 0)
    int   idx = 0x7fffffff;
    if (tid < NCAND) {
      int t = tid, r = 0;
      while (true) {
        int cnt = TOPK / (r + 1);
        if (t < cnt) break;
        t -= cnt;
        ++r;
      }
      int s = t;
      v   = aval[r] * sval[u][s];          // f32 rounding, matches reference
      idx = aidx[r] * DPN + sidx[u][s];    // flat index growth: i*DP + j
    }
    cval[tid] = v;
    cidx[tid] = idx;
    __syncthreads();

    int rank = 0;
    for (int j = 0; j < DPN; ++j) {
      float w = cval[j];
      rank += (w > v) || (w == v && cidx[j] < idx);
    }
    __syncthreads();  // all reads of aval/cval done before rewrite
    if (rank < TOPK) { aval[rank] = v; aidx[rank] = idx; }
    __syncthreads();
  }

  // ---- write: indices chunk (as float values) then weights chunk
  if (tid < TOPK) {
    out[row * TOPK + tid]            = (float)aidx[tid];
    out[NB * TOPK + row * TOPK + tid] = aval[tid];
  }
}

}  // namespace

extern "C" void kernel_launch(void* const* d_in, const int* in_sizes, int n_in,
                              void* d_out, int out_size, void* d_ws, size_t ws_size,
                              hipStream_t stream) {
  const float* z       = (const float*)d_in[0];
  const float* log_tau = (const float*)d_in[1];
  float* out           = (float*)d_out;
  hipLaunchKernelGGL(kron_topk_kernel, dim3(NB), dim3(DPN), 0, stream,
                     z, log_tau, out);
}